// Round 4
// baseline (1502.484 us; speedup 1.0000x reference)
//
#include <hip/hip_runtime.h>

// GCN layer: H = X @ W^T ; out = A_coo @ H     (N=50000, E=1600000, F=128)
//
// Pipeline: gemm (fp32 compute, bf16 H output, zeroes counters)
//        -> partition edges into 64-row bins (LDS-aggregated, run-coalesced)
//        -> binned SpMM: gather bf16 H rows, accumulate fp32 in LDS, no atomics
//           to global, full-line out stores.

constexpr int N_NODES = 50000;
constexpr int N_EDGES = 1600000;
constexpr int FEAT    = 128;

constexpr int ROWS_PER_BIN = 64;                                  // bin = row >> 6
constexpr int NB           = (N_NODES + ROWS_PER_BIN - 1) / ROWS_PER_BIN;  // 782
constexpr int CAP          = 2560;   // mean 2046, sd 45 -> 11 sigma headroom
constexpr int CHUNK        = 4096;   // edges per partition block
constexpr int PART_BLOCKS  = (N_EDGES + CHUNK - 1) / CHUNK;       // 391
constexpr int GEMM_BLOCKS  = (N_NODES + 63) / 64;                 // 782
constexpr int OVF_CAP      = 8192;

__device__ __forceinline__ unsigned short f2bf(float x) {
    unsigned u = __float_as_uint(x);
    u += 0x7fffu + ((u >> 16) & 1u);   // round to nearest even
    return (unsigned short)(u >> 16);
}
__device__ __forceinline__ float bf2f(unsigned short s) {
    return __uint_as_float(((unsigned)s) << 16);
}

// ---------------------------------------------------------------------------
// GEMM: Hb[n,o] = bf16( sum_k X[n,k]*W[o,k] ). 64x128 tile, 256 thr, 4x8.
// Thread cols = {2*tx+32*p+s}: pairs -> bf16x2 packed stores; LDS reads stay
// broadcast/2-way (free). Also zeroes zbuf (bin cursors + ovf counter).
// ---------------------------------------------------------------------------
__global__ __launch_bounds__(256) void gemm_xwt_bf16(
    const float* __restrict__ X, const float* __restrict__ W,
    unsigned short* __restrict__ Hb, int* __restrict__ zbuf, int zn) {
    int zt = blockIdx.x * 256 + threadIdx.x;
    if (zt < zn) zbuf[zt] = 0;

    constexpr int BM = 64, BK = 32;
    __shared__ float Xs[BM][BK + 1];
    __shared__ float Ws[FEAT][BK + 1];

    const int tid = threadIdx.x;
    const int tx  = tid & 15;
    const int ty  = tid >> 4;
    const int row0 = blockIdx.x * BM;

    float acc[4][8];
#pragma unroll
    for (int i = 0; i < 4; i++)
#pragma unroll
        for (int j = 0; j < 8; j++) acc[i][j] = 0.f;

    for (int kt = 0; kt < FEAT; kt += BK) {
#pragma unroll
        for (int t = 0; t < 2; t++) {
            int idx = tid + 256 * t;
            int r   = idx >> 3;
            int kq  = (idx & 7) << 2;
            int gr  = row0 + r;
            if (gr >= N_NODES) gr = N_NODES - 1;
            const float4 v = *(const float4*)&X[gr * FEAT + kt + kq];
            Xs[r][kq + 0] = v.x; Xs[r][kq + 1] = v.y;
            Xs[r][kq + 2] = v.z; Xs[r][kq + 3] = v.w;
        }
#pragma unroll
        for (int t = 0; t < 4; t++) {
            int idx = tid + 256 * t;
            int r   = idx >> 3;
            int kq  = (idx & 7) << 2;
            const float4 v = *(const float4*)&W[r * FEAT + kt + kq];
            Ws[r][kq + 0] = v.x; Ws[r][kq + 1] = v.y;
            Ws[r][kq + 2] = v.z; Ws[r][kq + 3] = v.w;
        }
        __syncthreads();

#pragma unroll
        for (int k = 0; k < BK; k++) {
            float xv[4], wv[8];
#pragma unroll
            for (int i = 0; i < 4; i++) xv[i] = Xs[ty * 4 + i][k];
#pragma unroll
            for (int p = 0; p < 4; p++) {
                wv[2 * p + 0] = Ws[2 * tx + 32 * p + 0][k];
                wv[2 * p + 1] = Ws[2 * tx + 32 * p + 1][k];
            }
#pragma unroll
            for (int i = 0; i < 4; i++)
#pragma unroll
                for (int j = 0; j < 8; j++) acc[i][j] += xv[i] * wv[j];
        }
        __syncthreads();
    }

    unsigned* Hb2 = (unsigned*)Hb;   // packed bf16 pairs
#pragma unroll
    for (int i = 0; i < 4; i++) {
        int gr = row0 + ty * 4 + i;
        if (gr < N_NODES) {
#pragma unroll
            for (int p = 0; p < 4; p++) {
                unsigned lo = f2bf(acc[i][2 * p + 0]);
                unsigned hi = f2bf(acc[i][2 * p + 1]);
                Hb2[gr * 64 + tx + 16 * p] = lo | (hi << 16);
            }
        }
    }
}

// ---------------------------------------------------------------------------
// Partition: edges -> bins (bin = row>>6). LDS hist per block, one global
// atomic per (block,bin), then placement with block-local consecutive runs.
// Entry: low32 = (rowLocal<<16)|col, high32 = val bits.
// ---------------------------------------------------------------------------
__global__ __launch_bounds__(256) void partition_edges(
    const int* __restrict__ rows, const int* __restrict__ cols,
    const float* __restrict__ vals,
    int* __restrict__ gcur, long long* __restrict__ binbuf,
    int* __restrict__ ovf_cnt, int* __restrict__ ovf) {
    __shared__ int hist[NB];
    __shared__ int wbase[NB];
    const int tid = threadIdx.x;
    const int e0  = blockIdx.x * CHUNK;

    for (int i = tid; i < NB; i += 256) hist[i] = 0;
    __syncthreads();

    int myrow[16];
#pragma unroll
    for (int t = 0; t < 16; t++) {
        int e = e0 + t * 256 + tid;
        int r = (e < N_EDGES) ? rows[e] : -1;
        myrow[t] = r;
        if (r >= 0) atomicAdd(&hist[r >> 6], 1);
    }
    __syncthreads();

    for (int i = tid; i < NB; i += 256) {
        int c = hist[i];
        wbase[i] = (c > 0) ? atomicAdd(&gcur[i], c) : 0;
        hist[i] = 0;   // reuse as block-local cursor
    }
    __syncthreads();

#pragma unroll
    for (int t = 0; t < 16; t++) {
        int e = e0 + t * 256 + tid;
        int r = myrow[t];
        if (r < 0) continue;
        int b    = r >> 6;
        int rank = wbase[b] + atomicAdd(&hist[b], 1);
        if (rank < CAP) {
            unsigned rc  = ((unsigned)(r & 63) << 16) | (unsigned)cols[e];
            long long m = ((long long)__float_as_int(vals[e]) << 32) | (long long)rc;
            binbuf[(size_t)b * CAP + rank] = m;
        } else {
            int k = atomicAdd(ovf_cnt, 1);
            if (k < OVF_CAP) ovf[k] = e;
        }
    }
}

// ---------------------------------------------------------------------------
// Binned SpMM: one block per bin. 64 rows x 128 feats fp32 acc in LDS (32KB).
// Lane owns feats {lane, lane+64} -> ds_add_f32 bank-conflict-free.
// Edge list staged 64-at-a-time per wave; 8-deep unrolled bf16 gathers.
// ---------------------------------------------------------------------------
__global__ __launch_bounds__(256) void spmm_bins(
    const int* __restrict__ gcur, const long long* __restrict__ binbuf,
    const unsigned short* __restrict__ Hb, float* __restrict__ out) {
    __shared__ float acc[ROWS_PER_BIN * FEAT];   // 32KB
    __shared__ long long est[4][64];

    const int b    = blockIdx.x;
    const int tid  = threadIdx.x;
    const int lane = tid & 63;
    const int w    = tid >> 6;

    float4* acc4 = (float4*)acc;
#pragma unroll
    for (int t = 0; t < 8; t++) acc4[tid + 256 * t] = make_float4(0.f, 0.f, 0.f, 0.f);
    __syncthreads();

    int cnt = gcur[b];
    if (cnt > CAP) cnt = CAP;
    const int q  = (cnt + 3) >> 2;
    const int s0 = w * q;
    const int s1 = (s0 + q) < cnt ? (s0 + q) : cnt;
    const long long* bb = binbuf + (size_t)b * CAP;

    for (int s = s0; s < s1; s += 64) {
        const int n = (s1 - s) < 64 ? (s1 - s) : 64;
        if (lane < n) est[w][lane] = bb[s + lane];
        int i = 0;
        for (; i + 8 <= n; i += 8) {
            float h0[8], h1[8], v[8];
            int   rl[8];
#pragma unroll
            for (int j = 0; j < 8; j++) {
                long long m = est[w][i + j];
                unsigned rc = (unsigned)m;
                int col = (int)(rc & 0xffffu);
                rl[j]   = (int)((rc >> 16) & 63u);
                v[j]    = __int_as_float((int)(m >> 32));
                h0[j]   = bf2f(Hb[col * FEAT + lane]);
                h1[j]   = bf2f(Hb[col * FEAT + 64 + lane]);
            }
#pragma unroll
            for (int j = 0; j < 8; j++) {
                atomicAdd(&acc[rl[j] * FEAT + lane],      v[j] * h0[j]);
                atomicAdd(&acc[rl[j] * FEAT + 64 + lane], v[j] * h1[j]);
            }
        }
        for (; i < n; i++) {
            long long m = est[w][i];
            unsigned rc = (unsigned)m;
            int col = (int)(rc & 0xffffu);
            int r   = (int)((rc >> 16) & 63u);
            float vv = __int_as_float((int)(m >> 32));
            atomicAdd(&acc[r * FEAT + lane],      vv * bf2f(Hb[col * FEAT + lane]));
            atomicAdd(&acc[r * FEAT + 64 + lane], vv * bf2f(Hb[col * FEAT + 64 + lane]));
        }
    }
    __syncthreads();

    const int row0 = b * ROWS_PER_BIN;
    float4* out4 = (float4*)out;
#pragma unroll
    for (int t = 0; t < 8; t++) {
        int idx = tid + 256 * t;        // float4 index within bin
        int r   = idx >> 5;             // 32 float4 per row
        int gr  = row0 + r;
        if (gr < N_NODES) out4[gr * 32 + (idx & 31)] = acc4[idx];
    }
}

// Overflow fixup (expected 0 entries; exact-correctness net).
__global__ void fixup_ovf(const int* __restrict__ ovf_cnt, const int* __restrict__ ovf,
                          const int* __restrict__ rows, const int* __restrict__ cols,
                          const float* __restrict__ vals,
                          const unsigned short* __restrict__ Hb, float* __restrict__ out) {
    int n = *ovf_cnt;
    if (n > OVF_CAP) n = OVF_CAP;
    for (int k = blockIdx.x; k < n; k += gridDim.x) {
        int e = ovf[k];
        int r = rows[e], c = cols[e];
        float v = vals[e];
        for (int f = threadIdx.x; f < FEAT; f += blockDim.x)
            atomicAdd(&out[r * FEAT + f], v * bf2f(Hb[c * FEAT + f]));
    }
}

// Fallback (tiny ws): push with global atomics. Correct, slow, rarely used.
__global__ __launch_bounds__(256) void spmm_push_atomic(
    const int* __restrict__ rows, const int* __restrict__ cols,
    const float* __restrict__ vals, const unsigned short* __restrict__ Hb,
    float* __restrict__ out) {
    const int e    = blockIdx.x * 4 + (threadIdx.x >> 6);
    const int lane = threadIdx.x & 63;
    if (e >= N_EDGES) return;
    int r = rows[e], c = cols[e];
    float v = vals[e];
    atomicAdd(&out[r * FEAT + lane],      v * bf2f(Hb[c * FEAT + lane]));
    atomicAdd(&out[r * FEAT + 64 + lane], v * bf2f(Hb[c * FEAT + 64 + lane]));
}

// ---------------------------------------------------------------------------
extern "C" void kernel_launch(void* const* d_in, const int* in_sizes, int n_in,
                              void* d_out, int out_size, void* d_ws, size_t ws_size,
                              hipStream_t stream) {
    const float* X      = (const float*)d_in[0];
    const float* W      = (const float*)d_in[1];
    const float* A_vals = (const float*)d_in[2];
    const int*   A_rows = (const int*)d_in[3];
    const int*   A_cols = (const int*)d_in[4];
    float* out = (float*)d_out;

    auto align256 = [](size_t x) { return (x + 255) & ~size_t(255); };
    char* ws = (char*)d_ws;

    size_t off = 0;
    size_t hb_off   = off; off += align256(size_t(N_NODES) * FEAT * 2);        // 12.8MB
    size_t gcur_off = off; off += align256(size_t(NB) * sizeof(int));
    size_t ovfc_off = off; off += 256;
    size_t ovf_off  = off; off += align256(size_t(OVF_CAP) * sizeof(int));
    size_t bin_off  = off; off += size_t(NB) * CAP * sizeof(long long);        // 16.0MB
    const size_t need = off;

    unsigned short* Hb = (unsigned short*)(ws + hb_off);

    if (ws_size >= need) {
        int*       gcur    = (int*)(ws + gcur_off);
        int*       ovf_cnt = (int*)(ws + ovfc_off);
        int*       ovf     = (int*)(ws + ovf_off);
        long long* binbuf  = (long long*)(ws + bin_off);

        // gcur .. ovf_cnt are one contiguous int region; zero inside the GEMM.
        int zn = (int)((ovfc_off - gcur_off) / sizeof(int)) + 1;
        gemm_xwt_bf16<<<GEMM_BLOCKS, 256, 0, stream>>>(X, W, Hb, gcur, zn);
        partition_edges<<<PART_BLOCKS, 256, 0, stream>>>(A_rows, A_cols, A_vals,
                                                         gcur, binbuf, ovf_cnt, ovf);
        spmm_bins<<<NB, 256, 0, stream>>>(gcur, binbuf, Hb, out);
        fixup_ovf<<<16, 256, 0, stream>>>(ovf_cnt, ovf, A_rows, A_cols, A_vals, Hb, out);
    } else {
        // Safety path: bf16 H + atomic push.
        gemm_xwt_bf16<<<GEMM_BLOCKS, 256, 0, stream>>>(X, W, Hb, (int*)(ws + hb_off), 0);
        hipMemsetAsync(out, 0, size_t(N_NODES) * FEAT * sizeof(float), stream);
        spmm_push_atomic<<<(N_EDGES + 3) / 4, 256, 0, stream>>>(A_rows, A_cols, A_vals, Hb, out);
    }
}

// Round 5
// 227.129 us; speedup vs baseline: 6.6151x; 6.6151x over previous
//
#include <hip/hip_runtime.h>

// GCN layer: H = X @ W^T ; out = A_coo @ H     (N=50000, E=1600000, F=128)
//
// Pipeline: gemm (fp32 compute, bf16 H out, zeroes counters)
//        -> partition edges into 64-row bins (LDS hist + block-local ranks)
//        -> binned SpMM: counting-sort bin by rowLocal in LDS (int atomics
//           only), then register accumulation per row — NO fp atomics anywhere.

constexpr int N_NODES = 50000;
constexpr int N_EDGES = 1600000;
constexpr int FEAT    = 128;

constexpr int ROWS_PER_BIN = 64;                                  // bin = row >> 6
constexpr int NB           = (N_NODES + ROWS_PER_BIN - 1) / ROWS_PER_BIN;  // 782
constexpr int CAP          = 2560;   // mean 2046, sd ~45 -> 11 sigma headroom
constexpr int CHUNK        = 4096;   // edges per partition block
constexpr int PART_BLOCKS  = (N_EDGES + CHUNK - 1) / CHUNK;       // 391
constexpr int GEMM_BLOCKS  = (N_NODES + 63) / 64;                 // 782
constexpr int OVF_CAP      = 8192;

__device__ __forceinline__ unsigned short f2bf(float x) {
    unsigned u = __float_as_uint(x);
    u += 0x7fffu + ((u >> 16) & 1u);   // round to nearest even
    return (unsigned short)(u >> 16);
}
__device__ __forceinline__ float bf2f(unsigned short s) {
    return __uint_as_float(((unsigned)s) << 16);
}

// ---------------------------------------------------------------------------
// GEMM: Hb[n,o] = bf16( sum_k X[n,k]*W[o,k] ). 64x128 tile, 256 thr, 4x8.
// Thread cols {2*tx+32*p+s} -> packed bf16x2 stores. Also zeroes zbuf.
// ---------------------------------------------------------------------------
__global__ __launch_bounds__(256) void gemm_xwt_bf16(
    const float* __restrict__ X, const float* __restrict__ W,
    unsigned short* __restrict__ Hb, int* __restrict__ zbuf, int zn) {
    int zt = blockIdx.x * 256 + threadIdx.x;
    if (zt < zn) zbuf[zt] = 0;

    constexpr int BM = 64, BK = 32;
    __shared__ float Xs[BM][BK + 1];
    __shared__ float Ws[FEAT][BK + 1];

    const int tid = threadIdx.x;
    const int tx  = tid & 15;
    const int ty  = tid >> 4;
    const int row0 = blockIdx.x * BM;

    float acc[4][8];
#pragma unroll
    for (int i = 0; i < 4; i++)
#pragma unroll
        for (int j = 0; j < 8; j++) acc[i][j] = 0.f;

    for (int kt = 0; kt < FEAT; kt += BK) {
#pragma unroll
        for (int t = 0; t < 2; t++) {
            int idx = tid + 256 * t;
            int r   = idx >> 3;
            int kq  = (idx & 7) << 2;
            int gr  = row0 + r;
            if (gr >= N_NODES) gr = N_NODES - 1;
            const float4 v = *(const float4*)&X[gr * FEAT + kt + kq];
            Xs[r][kq + 0] = v.x; Xs[r][kq + 1] = v.y;
            Xs[r][kq + 2] = v.z; Xs[r][kq + 3] = v.w;
        }
#pragma unroll
        for (int t = 0; t < 4; t++) {
            int idx = tid + 256 * t;
            int r   = idx >> 3;
            int kq  = (idx & 7) << 2;
            const float4 v = *(const float4*)&W[r * FEAT + kt + kq];
            Ws[r][kq + 0] = v.x; Ws[r][kq + 1] = v.y;
            Ws[r][kq + 2] = v.z; Ws[r][kq + 3] = v.w;
        }
        __syncthreads();

#pragma unroll
        for (int k = 0; k < BK; k++) {
            float xv[4], wv[8];
#pragma unroll
            for (int i = 0; i < 4; i++) xv[i] = Xs[ty * 4 + i][k];
#pragma unroll
            for (int p = 0; p < 4; p++) {
                wv[2 * p + 0] = Ws[2 * tx + 32 * p + 0][k];
                wv[2 * p + 1] = Ws[2 * tx + 32 * p + 1][k];
            }
#pragma unroll
            for (int i = 0; i < 4; i++)
#pragma unroll
                for (int j = 0; j < 8; j++) acc[i][j] += xv[i] * wv[j];
        }
        __syncthreads();
    }

    unsigned* Hb2 = (unsigned*)Hb;   // packed bf16 pairs
#pragma unroll
    for (int i = 0; i < 4; i++) {
        int gr = row0 + ty * 4 + i;
        if (gr < N_NODES) {
#pragma unroll
            for (int p = 0; p < 4; p++) {
                unsigned lo = f2bf(acc[i][2 * p + 0]);
                unsigned hi = f2bf(acc[i][2 * p + 1]);
                Hb2[gr * 64 + tx + 16 * p] = lo | (hi << 16);
            }
        }
    }
}

// ---------------------------------------------------------------------------
// Partition: edges -> bins (bin = row>>6). One counting pass computes
// block-local ranks; one global atomic per (block,bin); placement writes
// block-consecutive runs. Entry: low32 = (rowLocal<<16)|col, high32 = val.
// ---------------------------------------------------------------------------
__global__ __launch_bounds__(256) void partition_edges(
    const int* __restrict__ rows, const int* __restrict__ cols,
    const float* __restrict__ vals,
    int* __restrict__ gcur, long long* __restrict__ binbuf,
    int* __restrict__ ovf_cnt, int* __restrict__ ovf) {
    __shared__ int hist[NB];
    __shared__ int wbase[NB];
    const int tid = threadIdx.x;
    const int e0  = blockIdx.x * CHUNK;

    for (int i = tid; i < NB; i += 256) hist[i] = 0;
    __syncthreads();

    int myrow[16], myrank[16];
#pragma unroll
    for (int t = 0; t < 16; t++) {
        int e = e0 + t * 256 + tid;
        int r = (e < N_EDGES) ? rows[e] : -1;
        myrow[t] = r;
        myrank[t] = (r >= 0) ? atomicAdd(&hist[r >> 6], 1) : 0;
    }
    __syncthreads();

    for (int i = tid; i < NB; i += 256) {
        int c = hist[i];
        wbase[i] = (c > 0) ? atomicAdd(&gcur[i], c) : 0;
    }
    __syncthreads();

#pragma unroll
    for (int t = 0; t < 16; t++) {
        int e = e0 + t * 256 + tid;
        int r = myrow[t];
        if (r < 0) continue;
        int b    = r >> 6;
        int rank = wbase[b] + myrank[t];
        if (rank < CAP) {
            unsigned rc  = ((unsigned)(r & 63) << 16) | (unsigned)cols[e];
            long long m = ((long long)__float_as_int(vals[e]) << 32) | (long long)rc;
            binbuf[(size_t)b * CAP + rank] = m;
        } else {
            int k = atomicAdd(ovf_cnt, 1);
            if (k < OVF_CAP) ovf[k] = e;
        }
    }
}

// ---------------------------------------------------------------------------
// Binned SpMM v2: one block per bin. Counting-sort bin entries by rowLocal
// into LDS (int atomics only), then each wave owns 16 complete rows and
// accumulates in registers (float2/lane). One coalesced 256B ushort2 gather
// per edge, 8-deep unrolled. No fp atomics.
// ---------------------------------------------------------------------------
__global__ __launch_bounds__(256) void spmm_bins(
    const int* __restrict__ gcur, const long long* __restrict__ binbuf,
    const unsigned short* __restrict__ Hb, float* __restrict__ out) {
    __shared__ long long sorted[CAP];        // 20KB
    __shared__ int hist[ROWS_PER_BIN];       // counts -> exclusive starts
    __shared__ int cnt_of[ROWS_PER_BIN];
    __shared__ int cur[ROWS_PER_BIN];

    const int b    = blockIdx.x;
    const int tid  = threadIdx.x;
    const int lane = tid & 63;
    const int w    = tid >> 6;

    if (tid < ROWS_PER_BIN) { hist[tid] = 0; cur[tid] = 0; }
    __syncthreads();

    int cnt = gcur[b];
    if (cnt > CAP) cnt = CAP;
    const long long* bb = binbuf + (size_t)b * CAP;

    // count
    for (int i = tid; i < cnt; i += 256) {
        long long m = bb[i];
        int rl = (int)(((unsigned)m >> 16) & 63u);
        atomicAdd(&hist[rl], 1);
    }
    __syncthreads();

    // exclusive scan of 64 counts (wave 0)
    if (w == 0) {
        int c = hist[lane];
        cnt_of[lane] = c;
        int v = c;
#pragma unroll
        for (int off = 1; off < 64; off <<= 1) {
            int u = __shfl_up(v, off);
            if (lane >= off) v += u;
        }
        hist[lane] = v - c;   // exclusive start
    }
    __syncthreads();

    // scatter into sorted order
    for (int i = tid; i < cnt; i += 256) {
        long long m = bb[i];
        int rl  = (int)(((unsigned)m >> 16) & 63u);
        int pos = hist[rl] + atomicAdd(&cur[rl], 1);
        sorted[pos] = m;
    }
    __syncthreads();

    // per-row register accumulation; wave w owns rows [w*16, w*16+16)
    const int row0 = b * ROWS_PER_BIN;
    const ushort2* __restrict__ Hb2 = (const ushort2*)Hb;
    float2* out2 = (float2*)out;

    for (int rr = 0; rr < 16; rr++) {
        const int rl = w * 16 + rr;
        const int gr = row0 + rl;
        if (gr >= N_NODES) break;
        const int s = hist[rl];
        const int e = s + cnt_of[rl];

        float accx = 0.f, accy = 0.f;
        int i = s;
        for (; i + 8 <= e; i += 8) {
            float v[8];
            ushort2 h[8];
#pragma unroll
            for (int j = 0; j < 8; j++) {
                long long m = sorted[i + j];               // wave-uniform LDS broadcast
                int col = (int)((unsigned)m & 0xffffu);
                v[j] = __int_as_float((int)(m >> 32));
                h[j] = Hb2[col * 64 + lane];               // 4B/lane, 256B/wave
            }
#pragma unroll
            for (int j = 0; j < 8; j++) {
                accx += v[j] * bf2f(h[j].x);
                accy += v[j] * bf2f(h[j].y);
            }
        }
        for (; i < e; i++) {
            long long m = sorted[i];
            int col = (int)((unsigned)m & 0xffffu);
            float vv = __int_as_float((int)(m >> 32));
            ushort2 hh = Hb2[col * 64 + lane];
            accx += vv * bf2f(hh.x);
            accy += vv * bf2f(hh.y);
        }
        out2[gr * 64 + lane] = make_float2(accx, accy);    // 512B/row coalesced
    }
}

// Overflow fixup (expected 0 entries; exact-correctness net).
__global__ void fixup_ovf(const int* __restrict__ ovf_cnt, const int* __restrict__ ovf,
                          const int* __restrict__ rows, const int* __restrict__ cols,
                          const float* __restrict__ vals,
                          const unsigned short* __restrict__ Hb, float* __restrict__ out) {
    int n = *ovf_cnt;
    if (n > OVF_CAP) n = OVF_CAP;
    for (int k = blockIdx.x; k < n; k += gridDim.x) {
        int e = ovf[k];
        int r = rows[e], c = cols[e];
        float v = vals[e];
        for (int f = threadIdx.x; f < FEAT; f += blockDim.x)
            atomicAdd(&out[r * FEAT + f], v * bf2f(Hb[c * FEAT + f]));
    }
}

// Fallback (tiny ws): push with global atomics. Correct, slow, rarely used.
__global__ __launch_bounds__(256) void spmm_push_atomic(
    const int* __restrict__ rows, const int* __restrict__ cols,
    const float* __restrict__ vals, const unsigned short* __restrict__ Hb,
    float* __restrict__ out) {
    const int e    = blockIdx.x * 4 + (threadIdx.x >> 6);
    const int lane = threadIdx.x & 63;
    if (e >= N_EDGES) return;
    int r = rows[e], c = cols[e];
    float v = vals[e];
    atomicAdd(&out[r * FEAT + lane],      v * bf2f(Hb[c * FEAT + lane]));
    atomicAdd(&out[r * FEAT + 64 + lane], v * bf2f(Hb[c * FEAT + 64 + lane]));
}

// ---------------------------------------------------------------------------
extern "C" void kernel_launch(void* const* d_in, const int* in_sizes, int n_in,
                              void* d_out, int out_size, void* d_ws, size_t ws_size,
                              hipStream_t stream) {
    const float* X      = (const float*)d_in[0];
    const float* W      = (const float*)d_in[1];
    const float* A_vals = (const float*)d_in[2];
    const int*   A_rows = (const int*)d_in[3];
    const int*   A_cols = (const int*)d_in[4];
    float* out = (float*)d_out;

    auto align256 = [](size_t x) { return (x + 255) & ~size_t(255); };
    char* ws = (char*)d_ws;

    size_t off = 0;
    size_t hb_off   = off; off += align256(size_t(N_NODES) * FEAT * 2);        // 12.8MB
    size_t gcur_off = off; off += align256(size_t(NB) * sizeof(int));
    size_t ovfc_off = off; off += 256;
    size_t ovf_off  = off; off += align256(size_t(OVF_CAP) * sizeof(int));
    size_t bin_off  = off; off += size_t(NB) * CAP * sizeof(long long);        // 16.0MB
    const size_t need = off;

    unsigned short* Hb = (unsigned short*)(ws + hb_off);

    if (ws_size >= need) {
        int*       gcur    = (int*)(ws + gcur_off);
        int*       ovf_cnt = (int*)(ws + ovfc_off);
        int*       ovf     = (int*)(ws + ovf_off);
        long long* binbuf  = (long long*)(ws + bin_off);

        // gcur .. ovf_cnt are one contiguous int region; zero inside the GEMM.
        int zn = (int)((ovfc_off - gcur_off) / sizeof(int)) + 1;
        gemm_xwt_bf16<<<GEMM_BLOCKS, 256, 0, stream>>>(X, W, Hb, gcur, zn);
        partition_edges<<<PART_BLOCKS, 256, 0, stream>>>(A_rows, A_cols, A_vals,
                                                         gcur, binbuf, ovf_cnt, ovf);
        spmm_bins<<<NB, 256, 0, stream>>>(gcur, binbuf, Hb, out);
        fixup_ovf<<<16, 256, 0, stream>>>(ovf_cnt, ovf, A_rows, A_cols, A_vals, Hb, out);
    } else {
        // Safety path: bf16 H + atomic push.
        gemm_xwt_bf16<<<GEMM_BLOCKS, 256, 0, stream>>>(X, W, Hb, (int*)(ws + hb_off), 0);
        hipMemsetAsync(out, 0, size_t(N_NODES) * FEAT * sizeof(float), stream);
        spmm_push_atomic<<<(N_EDGES + 3) / 4, 256, 0, stream>>>(A_rows, A_cols, A_vals, Hb, out);
    }
}